// Round 1
// baseline (330.110 us; speedup 1.0000x reference)
//
#include <hip/hip_runtime.h>
#include <hip/hip_bf16.h>

typedef __bf16 bf16x8 __attribute__((ext_vector_type(8)));
typedef float  f32x4  __attribute__((ext_vector_type(4)));

#define NB   64      // batch
#define NPTS 10000   // nodes
#define KC0  128     // feature channels (GEMM K)
#define NC1  64      // kernel MLP out channels
#define NC2  256     // encoder out channels (GEMM N)
#define GN   4       // n-values per block

// ---------------------------------------------------------------------------
// Kernel 1: tiny precompute.
//   k0   = MLP(0)                                  [64]  (exact fp32)
//   cst  = k0 @ We[128:192,:] + be                 [256] (exact fp32)
//   WeT  = bf16(We[0:128,:])^T  -> [256][128]      (B-operand, transposed)
// ---------------------------------------------------------------------------
__global__ __launch_bounds__(256) void pe_precompute(
    const float* __restrict__ b1, const float* __restrict__ W2,
    const float* __restrict__ b2, const float* __restrict__ W3,
    const float* __restrict__ b3, const float* __restrict__ We,
    const float* __restrict__ be,
    __hip_bfloat16* __restrict__ WeT, float* __restrict__ cst)
{
    __shared__ float k0[NC1];
    const int t = threadIdx.x;

    if (t < NC1) {
        float h1[8], h2[16];
        #pragma unroll
        for (int i = 0; i < 8; ++i) h1[i] = fmaxf(b1[i], 0.f);  // x=0 -> relu(b1)
        #pragma unroll
        for (int j = 0; j < 16; ++j) {
            float s = b2[j];
            #pragma unroll
            for (int i = 0; i < 8; ++i) s += h1[i] * W2[i * 16 + j];
            h2[j] = fmaxf(s, 0.f);
        }
        float s = b3[t];
        #pragma unroll
        for (int j = 0; j < 16; ++j) s += h2[j] * W3[j * NC1 + t];
        k0[t] = s;
    }
    __syncthreads();

    // cst[c] = be[c] + sum_j k0[j] * We[(128+j)*256 + c]   (t = c, 256 threads)
    {
        float s = be[t];
        for (int j = 0; j < NC1; ++j)
            s += k0[j] * We[(size_t)(KC0 + j) * NC2 + t];
        cst[t] = s;
    }
    // WeT[c][k] = bf16(We[k][c])
    {
        for (int k = 0; k < KC0; ++k)
            WeT[(size_t)t * KC0 + k] = __float2bfloat16(We[(size_t)k * NC2 + t]);
    }
}

// ---------------------------------------------------------------------------
// Kernel 2: out[n,b,c] = feature[b,n,:] @ We[:128,c] + cst[c]
// 2500 blocks x 256 threads. Block: 4 consecutive n, all 64 b, all 256 c.
// Wave w owns columns [w*64, w*64+64). B fragments live in registers for the
// whole block (no LDS, no barriers). A is read fp32 direct-to-reg, cvt bf16.
// MFMA 16x16x32 layouts (m89-verified):
//   A: lane l -> A[l&15][8*(l>>4)+j]   B: lane l -> B[8*(l>>4)+j][l&15]
//   D: lane l, reg r -> D[(l>>4)*4+r][l&15]
// ---------------------------------------------------------------------------
__global__ __launch_bounds__(256) void pe_gemm(
    const float* __restrict__ feat, const __hip_bfloat16* __restrict__ WeT,
    const float* __restrict__ cst, float* __restrict__ out)
{
    const int wave  = threadIdx.x >> 6;
    const int lane  = threadIdx.x & 63;
    const int lm    = lane & 15;   // row (A) / col (B,D) within fragment
    const int lk    = lane >> 4;   // k-group
    const int cbase = wave * 64;
    const int n0    = blockIdx.x * GN;

    // B fragments: bfrag[kk][nn], 16B contiguous loads from transposed WeT
    bf16x8 bfrag[4][4];
    #pragma unroll
    for (int nn = 0; nn < 4; ++nn) {
        const int c = cbase + nn * 16 + lm;
        #pragma unroll
        for (int kk = 0; kk < 4; ++kk)
            bfrag[kk][nn] = *reinterpret_cast<const bf16x8*>(
                WeT + (size_t)c * KC0 + kk * 32 + lk * 8);
    }
    // per-column constant (same for all 4 acc rows of a lane)
    float cv[4];
    #pragma unroll
    for (int nn = 0; nn < 4; ++nn) cv[nn] = cst[cbase + nn * 16 + lm];

    for (int g = 0; g < GN; ++g) {
        const size_t n = (size_t)n0 + g;
        #pragma unroll
        for (int mm = 0; mm < 4; ++mm) {
            const int brow = mm * 16;
            const float* ap = feat + ((size_t)(brow + lm) * NPTS + n) * KC0 + lk * 8;

            bf16x8 afrag[4];
            #pragma unroll
            for (int kk = 0; kk < 4; ++kk) {
                f32x4 lo = *reinterpret_cast<const f32x4*>(ap + kk * 32);
                f32x4 hi = *reinterpret_cast<const f32x4*>(ap + kk * 32 + 4);
                bf16x8 v;
                #pragma unroll
                for (int j = 0; j < 4; ++j) {
                    v[j]     = (__bf16)lo[j];
                    v[j + 4] = (__bf16)hi[j];
                }
                afrag[kk] = v;
            }

            f32x4 acc[4];
            #pragma unroll
            for (int nn = 0; nn < 4; ++nn)
                acc[nn] = (f32x4){cv[nn], cv[nn], cv[nn], cv[nn]};

            #pragma unroll
            for (int kk = 0; kk < 4; ++kk)
                #pragma unroll
                for (int nn = 0; nn < 4; ++nn)
                    acc[nn] = __builtin_amdgcn_mfma_f32_16x16x32_bf16(
                        afrag[kk], bfrag[kk][nn], acc[nn], 0, 0, 0);

            // out[n, brow + lk*4 + r, cbase + nn*16 + lm]
            float* op = out + (n * NB + brow + lk * 4) * NC2 + cbase + lm;
            #pragma unroll
            for (int nn = 0; nn < 4; ++nn)
                #pragma unroll
                for (int r = 0; r < 4; ++r)
                    op[(size_t)r * NC2 + nn * 16] = acc[nn][r];
        }
    }
}

extern "C" void kernel_launch(void* const* d_in, const int* in_sizes, int n_in,
                              void* d_out, int out_size, void* d_ws, size_t ws_size,
                              hipStream_t stream) {
    const float* feat = (const float*)d_in[0];
    // d_in[1] = coordinates: unused (MLP input is identically zero)
    // d_in[2] = W1: unused (multiplies the zero vector)
    const float* b1 = (const float*)d_in[3];
    const float* W2 = (const float*)d_in[4];
    const float* b2 = (const float*)d_in[5];
    const float* W3 = (const float*)d_in[6];
    const float* b3 = (const float*)d_in[7];
    const float* We = (const float*)d_in[8];
    const float* be = (const float*)d_in[9];

    __hip_bfloat16* WeT = (__hip_bfloat16*)d_ws;                    // 256*128*2 = 64 KiB
    float*          cst = (float*)((char*)d_ws + NC2 * KC0 * 2);    // 256 floats

    pe_precompute<<<1, 256, 0, stream>>>(b1, W2, b2, W3, b3, We, be, WeT, cst);
    pe_gemm<<<NPTS / GN, 256, 0, stream>>>(feat, WeT, cst, (float*)d_out);
}

// Round 2
// 310.091 us; speedup vs baseline: 1.0646x; 1.0646x over previous
//
#include <hip/hip_runtime.h>
#include <hip/hip_bf16.h>

typedef __bf16 bf16x8 __attribute__((ext_vector_type(8)));
typedef float  f32x4  __attribute__((ext_vector_type(4)));

#define NB   64      // batch
#define NPTS 10000   // nodes
#define KC0  128     // feature channels (GEMM K)
#define NC1  64      // kernel MLP out channels
#define NC2  256     // encoder out channels (GEMM M after swap)
#define GN   4       // n-values per block
#define LDSPAD 4
#define LROW (NC2 + LDSPAD)   // 260 floats per LDS row (breaks pow2 bank stride)

// ---------------------------------------------------------------------------
// Kernel 1: precompute, parallelized over 9 blocks.
//   block 0 : k0 = MLP(0); cst = k0 @ We[128:192,:] + be   [256] exact fp32
//   block b : WeT slice — WeT[c][k] = bf16(We[k][c]), k in [(b-1)*16,(b-1)*16+16)
// ---------------------------------------------------------------------------
__global__ __launch_bounds__(256) void pe_precompute(
    const float* __restrict__ b1, const float* __restrict__ W2,
    const float* __restrict__ b2, const float* __restrict__ W3,
    const float* __restrict__ b3, const float* __restrict__ We,
    const float* __restrict__ be,
    __hip_bfloat16* __restrict__ WeT, float* __restrict__ cst)
{
    const int t  = threadIdx.x;
    const int bb = blockIdx.x;
    if (bb == 0) {
        __shared__ float sW2[8 * 16], sW3[16 * NC1], sb1[8], sb2[16], sb3[NC1], k0[NC1];
        if (t < 128) sW2[t] = W2[t];
        for (int i = t; i < 16 * NC1; i += 256) sW3[i] = W3[i];
        if (t < 8)  sb1[t] = b1[t];
        if (t < 16) sb2[t] = b2[t];
        if (t < NC1) sb3[t] = b3[t];
        __syncthreads();
        if (t < NC1) {
            float h1[8], h2[16];
            #pragma unroll
            for (int i = 0; i < 8; ++i) h1[i] = fmaxf(sb1[i], 0.f);  // x=0 -> relu(b1)
            #pragma unroll
            for (int j = 0; j < 16; ++j) {
                float s = sb2[j];
                #pragma unroll
                for (int i = 0; i < 8; ++i) s += h1[i] * sW2[i * 16 + j];
                h2[j] = fmaxf(s, 0.f);
            }
            float s = sb3[t];
            #pragma unroll
            for (int j = 0; j < 16; ++j) s += h2[j] * sW3[j * NC1 + t];
            k0[t] = s;
        }
        __syncthreads();
        float s = be[t];
        #pragma unroll 8
        for (int j = 0; j < NC1; ++j)
            s += k0[j] * We[(size_t)(KC0 + j) * NC2 + t];
        cst[t] = s;
    } else {
        const int kbase = (bb - 1) * 16;
        #pragma unroll
        for (int kr = 0; kr < 16; ++kr) {
            const int k = kbase + kr;
            WeT[(size_t)t * KC0 + k] = __float2bfloat16(We[(size_t)k * NC2 + t]);
        }
    }
}

// ---------------------------------------------------------------------------
// Kernel 2: out[n,b,c] = feature[b,n,:] @ We[:128,c] + cst[c]
// Swapped operands: A = WeT fragment (c x k), B = feature fragment (k x b),
// so D = [c][b] and each lane's 4 acc regs are 4 CONSECUTIVE c values.
// MFMA 16x16x32 layouts (m89-verified):
//   A: lane l -> A[l&15][8*(l>>4)+j]       (c = lm, k = lk*8+j)
//   B: lane l -> B[8*(l>>4)+j][l&15]       (k = lk*8+j, b = lm)
//   D: lane l, reg r -> D[(l>>4)*4+r][l&15] (c = lk*4+r, b = lm)
// Epilogue: acc -> LDS (padded), then each wave streams one full 1KB row per
// global_store_dwordx4 instruction -> full-line coalesced writes, no RFO.
// ---------------------------------------------------------------------------
__global__ __launch_bounds__(256) void pe_gemm(
    const float* __restrict__ feat, const __hip_bfloat16* __restrict__ WeT,
    const float* __restrict__ cst, float* __restrict__ out)
{
    __shared__ float lds[32 * LROW];
    const int tid  = threadIdx.x;
    const int wave = tid >> 6;
    const int lane = tid & 63;
    const int lm   = lane & 15;
    const int lk   = lane >> 4;
    const int cbase = wave * 64;

    // A fragments (WeT), held in registers for the whole block
    bf16x8 afrag[4][4];
    #pragma unroll
    for (int nn = 0; nn < 4; ++nn) {
        const __hip_bfloat16* wp = WeT + (size_t)(cbase + nn * 16 + lm) * KC0 + lk * 8;
        #pragma unroll
        for (int kk = 0; kk < 4; ++kk)
            afrag[kk][nn] = *reinterpret_cast<const bf16x8*>(wp + kk * 32);
    }
    // constant bias: 4 consecutive c per lane -> one f32x4 per c-tile
    f32x4 cv[4];
    #pragma unroll
    for (int nn = 0; nn < 4; ++nn)
        cv[nn] = *reinterpret_cast<const f32x4*>(cst + cbase + nn * 16 + lk * 4);

    const int ocol = lane * 4;  // epilogue: col in floats

    for (int g = 0; g < GN; ++g) {
        const size_t n  = (size_t)blockIdx.x * GN + g;
        const float* fn = feat + n * KC0;
        #pragma unroll
        for (int h = 0; h < 2; ++h) {          // b-halves [0,32) and [32,64)
            #pragma unroll
            for (int mm = 0; mm < 2; ++mm) {   // b-tiles of 16
                const int brow = h * 32 + mm * 16 + lm;
                const float* ap = fn + (size_t)brow * ((size_t)NPTS * KC0) + lk * 8;

                bf16x8 bfr[4];
                #pragma unroll
                for (int kk = 0; kk < 4; ++kk) {
                    f32x4 lo = *reinterpret_cast<const f32x4*>(ap + kk * 32);
                    f32x4 hi = *reinterpret_cast<const f32x4*>(ap + kk * 32 + 4);
                    bf16x8 v;
                    #pragma unroll
                    for (int j = 0; j < 4; ++j) {
                        v[j]     = (__bf16)lo[j];
                        v[j + 4] = (__bf16)hi[j];
                    }
                    bfr[kk] = v;
                }

                f32x4 acc[4];
                #pragma unroll
                for (int nn = 0; nn < 4; ++nn) acc[nn] = cv[nn];
                #pragma unroll
                for (int kk = 0; kk < 4; ++kk)
                    #pragma unroll
                    for (int nn = 0; nn < 4; ++nn)
                        acc[nn] = __builtin_amdgcn_mfma_f32_16x16x32_bf16(
                            afrag[kk][nn], bfr[kk], acc[nn], 0, 0, 0);

                // acc[nn] = out rows c = cbase+nn*16+lk*4 .. +3, col b = brow
                float* lp = lds + (mm * 16 + lm) * LROW + cbase + lk * 4;
                #pragma unroll
                for (int nn = 0; nn < 4; ++nn)
                    *reinterpret_cast<f32x4*>(lp + nn * 16) = acc[nn];
            }
            __syncthreads();
            // stream 32 rows x 1KB: each wave writes one full row per pass
            float* ob = out + (n * NB + h * 32) * NC2;
            #pragma unroll
            for (int p = 0; p < 8; ++p) {
                const int row = p * 4 + wave;
                *reinterpret_cast<f32x4*>(ob + (size_t)row * NC2 + ocol) =
                    *reinterpret_cast<const f32x4*>(lds + row * LROW + ocol);
            }
            __syncthreads();
        }
    }
}

extern "C" void kernel_launch(void* const* d_in, const int* in_sizes, int n_in,
                              void* d_out, int out_size, void* d_ws, size_t ws_size,
                              hipStream_t stream) {
    const float* feat = (const float*)d_in[0];
    // d_in[1] = coordinates: unused (MLP input is identically zero)
    // d_in[2] = W1: unused (multiplies the zero vector)
    const float* b1 = (const float*)d_in[3];
    const float* W2 = (const float*)d_in[4];
    const float* b2 = (const float*)d_in[5];
    const float* W3 = (const float*)d_in[6];
    const float* b3 = (const float*)d_in[7];
    const float* We = (const float*)d_in[8];
    const float* be = (const float*)d_in[9];

    __hip_bfloat16* WeT = (__hip_bfloat16*)d_ws;                    // 256*128*2 = 64 KiB
    float*          cst = (float*)((char*)d_ws + NC2 * KC0 * 2);    // 256 floats, 16B-aligned

    pe_precompute<<<9, 256, 0, stream>>>(b1, W2, b2, W3, b3, We, be, WeT, cst);
    pe_gemm<<<NPTS / GN, 256, 0, stream>>>(feat, WeT, cst, (float*)d_out);
}